// Round 13
// baseline (257.231 us; speedup 1.0000x reference)
//
#include <hip/hip_runtime.h>

// ---------------------------------------------------------------------------
// WindowAttention fused kernel for MI355X (gfx950) — R12: token-split blocks
// B=1024 windows, N=64 tokens, C=256, H=8 heads, hd=32
// 2048 blocks x 256 thr (4 waves, 2 heads/wave). Block = (window, half):
// owns 32 token rows, ALL 8 heads. K/V/Vs/Vh projections computed full
// (duplicated across siblings, +50% MFMA); Q/attn/PV/out-proj row-split.
// LDS = 80KB (BO 16K O/q-half + A 32K + B 32K) -> 2 independent blocks/CU:
// one block's barrier/HBM stalls overlap the other's MFMA.
// launch_bounds(256,2): 256-reg cap (fits R4-sized state, audited ~200 peak).
// Siblings same-XCD + adjacent: win=(bid&7)|((bid>>4)<<3), hf=(bid>>3)&1.
// ---------------------------------------------------------------------------

typedef __attribute__((ext_vector_type(8))) __bf16 bf16x8;
typedef __attribute__((ext_vector_type(4))) float f32x4;
typedef __attribute__((ext_vector_type(4))) unsigned short u16x4;

__device__ __forceinline__ unsigned short f2bf(float f) {
  return __builtin_bit_cast(unsigned short, (__bf16)f);
}
__device__ __forceinline__ unsigned pk2(float lo, float hi) {
  return (unsigned)f2bf(lo) | ((unsigned)f2bf(hi) << 16);
}
__device__ __forceinline__ int swz256(int row, int col) {   // 256-elem (512B) rows
  return row * 256 + (col ^ ((row & 31) << 3));
}
__device__ __forceinline__ f32x4 mfma16(bf16x8 a, bf16x8 b, f32x4 c) {
  return __builtin_amdgcn_mfma_f32_16x16x32_bf16(a, b, c, 0, 0, 0);
}

// ---------------- pre-kernel 1: pack weights into fragment layout -----------
__global__ void pack_weights(const float* __restrict__ W0, const float* __restrict__ W1,
                             const float* __restrict__ W2, const float* __restrict__ W3,
                             const float* __restrict__ W4, const float* __restrict__ W5,
                             const float* __restrict__ W6, const float* __restrict__ W7,
                             unsigned short* __restrict__ pk) {
  int t = blockIdx.x * 256 + threadIdx.x;   // 65536 threads
  int mat = t >> 13;
  int w   = (t >> 11) & 3;
  int blk = (t >> 9) & 3;
  int kc  = (t >> 6) & 7;
  int l   = t & 63;
  const float* W = (mat == 0) ? W0 : (mat == 1) ? W1 : (mat == 2) ? W2 : (mat == 3) ? W3
                 : (mat == 4) ? W4 : (mat == 5) ? W5 : (mat == 6) ? W6 : W7;
  const float* src = W + (64 * w + 16 * blk + (l & 15)) * 256 + 32 * kc + 8 * (l >> 4);
  unsigned short* dst = pk + (size_t)t * 8;
#pragma unroll
  for (int i = 0; i < 8; ++i) dst[i] = f2bf(src[i]);
}

// ---------------- pre-kernel 2: bmt[wi][h][nf][mf][lane][r] -----------------
// value = mask[wi][q][k] + btab[ridx[q][k]][h], q=16nf+(l&15), k=16mf+4(l>>4)+r
__global__ void make_bmt(const float* __restrict__ mask, const float* __restrict__ btab,
                         const int* __restrict__ ridx, float* __restrict__ bmt) {
  int t = blockIdx.x * 256 + threadIdx.x;   // 2,097,152 threads
  int r  = t & 3;
  int l  = (t >> 2) & 63;
  int mf = (t >> 8) & 3;
  int nf = (t >> 10) & 3;
  int h  = (t >> 12) & 7;
  int wi = t >> 15;
  int q = 16 * nf + (l & 15);
  int k = 16 * mf + 4 * (l >> 4) + r;
  bmt[t] = mask[(wi * 64 + q) * 64 + k] + btab[ridx[q * 64 + k] * 8 + h];
}

// ---------------- butterfly: two 16-row C-layout blocks -> one frag ---------
__device__ __forceinline__ bf16x8 butterfly(f32x4 C0, f32x4 C1, int c4, int r16) {
  unsigned a0 = pk2(C0[0], C0[1]), a1 = pk2(C0[2], C0[3]);
  unsigned b0 = pk2(C1[0], C1[1]), b1 = pk2(C1[2], C1[3]);
  int src0 = (((2 * c4) & 3) << 4) + r16;
  int src1 = (((2 * c4 + 1) & 3) << 4) + r16;
  unsigned A0 = (unsigned)__shfl((int)a0, src0);
  unsigned A1 = (unsigned)__shfl((int)a1, src0);
  unsigned A2 = (unsigned)__shfl((int)a0, src1);
  unsigned A3 = (unsigned)__shfl((int)a1, src1);
  unsigned B0 = (unsigned)__shfl((int)b0, src0);
  unsigned B1 = (unsigned)__shfl((int)b1, src0);
  unsigned B2 = (unsigned)__shfl((int)b0, src1);
  unsigned B3 = (unsigned)__shfl((int)b1, src1);
  bool hi = c4 >= 2;
  union { unsigned u[4]; bf16x8 v; } r;
  r.u[0] = hi ? B0 : A0;
  r.u[1] = hi ? B1 : A1;
  r.u[2] = hi ? B2 : A2;
  r.u[3] = hi ? B3 : A3;
  return r.v;
}

// ---------------- staging (256 threads) -------------------------------------
// full 64-row tile: load both 32-reg chunks, compute may interleave, write late
__device__ __forceinline__ void load8(f32x4 r[8], const float* __restrict__ X,
                                      int win, int tid, int half) {
  const f32x4* src = reinterpret_cast<const f32x4*>(X + (size_t)win * 16384) + half * 2048;
#pragma unroll
  for (int it = 0; it < 8; ++it) r[it] = src[it * 256 + tid];
}
__device__ __forceinline__ void write8(unsigned short* T, const f32x4 r[8], int tid, int half) {
#pragma unroll
  for (int it = 0; it < 8; ++it) {
    int f = half * 2048 + it * 256 + tid;
    int row = f >> 6;
    int col = (f & 63) << 2;
    u16x4 p;
    p[0] = f2bf(r[it][0]); p[1] = f2bf(r[it][1]);
    p[2] = f2bf(r[it][2]); p[3] = f2bf(r[it][3]);
    *reinterpret_cast<u16x4*>(T + swz256(row, col)) = p;
  }
}
__device__ __forceinline__ void stage_tile(unsigned short* T, const float* __restrict__ X,
                                           int win, int tid) {
  f32x4 r0[8], r1[8];
  load8(r0, X, win, tid, 0);
  load8(r1, X, win, tid, 1);
  write8(T, r0, tid, 0);
  write8(T, r1, tid, 1);
}
// half tile (32 rows = block's token rows) -> BO [32][256]
__device__ __forceinline__ void stage_half(unsigned short* BO, const float* __restrict__ X,
                                           int win, int hf, int tid) {
  f32x4 r[8];
  const f32x4* src = reinterpret_cast<const f32x4*>(X + (size_t)win * 16384 + hf * 8192);
#pragma unroll
  for (int it = 0; it < 8; ++it) r[it] = src[it * 256 + tid];
#pragma unroll
  for (int it = 0; it < 8; ++it) {
    int f = it * 256 + tid;
    int row = f >> 6;                 // 0..31
    int col = (f & 63) << 2;
    u16x4 p;
    p[0] = f2bf(r[it][0]); p[1] = f2bf(r[it][1]);
    p[2] = f2bf(r[it][2]); p[3] = f2bf(r[it][3]);
    *reinterpret_cast<u16x4*>(BO + swz256(row, col)) = p;
  }
}

// per-wave packed-weight base: rows [64*w2, 64*w2+64) of mat
__device__ __forceinline__ const unsigned short* pwBase7(const unsigned short* pk,
                                                         int mat, int w2) {
  return pk + mat * 65536 + w2 * 16384;
}

// ---------------- transposed proj, full tile (2 heads) — R7-verified --------
__device__ __forceinline__ void projT2(const unsigned short* __restrict__ T,
                                       const unsigned short* __restrict__ pw,
                                       const float* __restrict__ bias, float scale,
                                       int lane, int w2, bf16x8 fA[4], bf16x8 fB[4]) {
  const int r16 = lane & 15, c4 = lane >> 4;
  f32x4 z = {0.f, 0.f, 0.f, 0.f};
  f32x4 acc[4][4];
#pragma unroll
  for (int j = 0; j < 4; ++j)
#pragma unroll
    for (int nf = 0; nf < 4; ++nf) acc[j][nf] = z;
  __builtin_amdgcn_s_setprio(1);
#pragma unroll
  for (int kc = 0; kc < 8; ++kc) {
    bf16x8 aw[4], bx[4];
#pragma unroll
    for (int j = 0; j < 4; ++j)
      aw[j] = *reinterpret_cast<const bf16x8*>(pw + (j * 8 + kc) * 512 + lane * 8);
#pragma unroll
    for (int nf = 0; nf < 4; ++nf)
      bx[nf] = *reinterpret_cast<const bf16x8*>(T + swz256(16 * nf + r16, 32 * kc + 8 * c4));
#pragma unroll
    for (int j = 0; j < 4; ++j)
#pragma unroll
      for (int nf = 0; nf < 4; ++nf) acc[j][nf] = mfma16(aw[j], bx[nf], acc[j][nf]);
  }
  __builtin_amdgcn_s_setprio(0);
#pragma unroll
  for (int j = 0; j < 4; ++j) {
    f32x4 b4 = *reinterpret_cast<const f32x4*>(bias + 64 * w2 + 16 * j + 4 * c4);
#pragma unroll
    for (int nf = 0; nf < 4; ++nf)
#pragma unroll
      for (int r = 0; r < 4; ++r) acc[j][nf][r] = (acc[j][nf][r] + b4[r]) * scale;
  }
#pragma unroll
  for (int nf = 0; nf < 4; ++nf) {
    fA[nf] = butterfly(acc[0][nf], acc[1][nf], c4, r16);
    fB[nf] = butterfly(acc[2][nf], acc[3][nf], c4, r16);
  }
}

// ---------------- transposed proj, half tile (q: 32 tokens, 2 heads) --------
__device__ __forceinline__ void projT2q(const unsigned short* __restrict__ BO,
                                        const unsigned short* __restrict__ pw,
                                        const float* __restrict__ bias, float scale,
                                        int lane, int w2, bf16x8 fA[2], bf16x8 fB[2]) {
  const int r16 = lane & 15, c4 = lane >> 4;
  f32x4 z = {0.f, 0.f, 0.f, 0.f};
  f32x4 acc[4][2];
#pragma unroll
  for (int j = 0; j < 4; ++j)
#pragma unroll
    for (int nf = 0; nf < 2; ++nf) acc[j][nf] = z;
  __builtin_amdgcn_s_setprio(1);
#pragma unroll
  for (int kc = 0; kc < 8; ++kc) {
    bf16x8 aw[4], bx[2];
#pragma unroll
    for (int j = 0; j < 4; ++j)
      aw[j] = *reinterpret_cast<const bf16x8*>(pw + (j * 8 + kc) * 512 + lane * 8);
#pragma unroll
    for (int nf = 0; nf < 2; ++nf)
      bx[nf] = *reinterpret_cast<const bf16x8*>(BO + swz256(16 * nf + r16, 32 * kc + 8 * c4));
#pragma unroll
    for (int j = 0; j < 4; ++j)
#pragma unroll
      for (int nf = 0; nf < 2; ++nf) acc[j][nf] = mfma16(aw[j], bx[nf], acc[j][nf]);
  }
  __builtin_amdgcn_s_setprio(0);
#pragma unroll
  for (int j = 0; j < 4; ++j) {
    f32x4 b4 = *reinterpret_cast<const f32x4*>(bias + 64 * w2 + 16 * j + 4 * c4);
#pragma unroll
    for (int nf = 0; nf < 2; ++nf)
#pragma unroll
      for (int r = 0; r < 4; ++r) acc[j][nf][r] = (acc[j][nf][r] + b4[r]) * scale;
  }
#pragma unroll
  for (int nf = 0; nf < 2; ++nf) {
    fA[nf] = butterfly(acc[0][nf], acc[1][nf], c4, r16);
    fB[nf] = butterfly(acc[2][nf], acc[3][nf], c4, r16);
  }
}

// ---------------- attention, half rows (one head) ----------------------------
// Qf2[2] covers q-tokens hf*32 + {0..31}; bm nf index = 2*hf + qb2
__device__ __forceinline__ void attn_half(const bf16x8 Qf2[2], const bf16x8 Kf[4],
                                          const float* __restrict__ bmb, int hf,
                                          int lane, bf16x8 Pf[2][2]) {
  const int r16 = lane & 15, c4 = lane >> 4;
  f32x4 z = {0.f, 0.f, 0.f, 0.f};
#pragma unroll
  for (int qb2 = 0; qb2 < 2; ++qb2) {
    f32x4 s[4];
    __builtin_amdgcn_s_setprio(1);
#pragma unroll
    for (int t = 0; t < 4; ++t) s[t] = mfma16(Kf[t], Qf2[qb2], z);
    __builtin_amdgcn_s_setprio(0);
    const int nfq = 2 * hf + qb2;
    float mx = -1e30f;
#pragma unroll
    for (int t = 0; t < 4; ++t) {
      f32x4 bm4 = *reinterpret_cast<const f32x4*>(bmb + (((nfq * 4 + t) * 64 + lane) << 2));
#pragma unroll
      for (int r = 0; r < 4; ++r) {
        s[t][r] += bm4[r];
        mx = fmaxf(mx, s[t][r]);
      }
    }
    mx = fmaxf(mx, __shfl_xor(mx, 16));
    mx = fmaxf(mx, __shfl_xor(mx, 32));
    float sum = 0.f;
#pragma unroll
    for (int t = 0; t < 4; ++t)
#pragma unroll
      for (int r = 0; r < 4; ++r) {
        s[t][r] = __expf(s[t][r] - mx);
        sum += s[t][r];
      }
    sum += __shfl_xor(sum, 16);
    sum += __shfl_xor(sum, 32);
    float inv = 1.0f / sum;
#pragma unroll
    for (int kc = 0; kc < 2; ++kc) {
      f32x4 p0, p1;
#pragma unroll
      for (int r = 0; r < 4; ++r) {
        p0[r] = s[2 * kc][r] * inv;
        p1[r] = s[2 * kc + 1][r] * inv;
      }
      Pf[qb2][kc] = butterfly(p0, p1, c4, r16);
    }
  }
}

// ---------------- normal proj, full tile, 64 cols/wave — R7-verified --------
__device__ __forceinline__ void projN64(const unsigned short* __restrict__ T,
                                        const unsigned short* __restrict__ pw,
                                        int lane, f32x4 acc[4][4]) {
  const int r16 = lane & 15, c4 = lane >> 4;
  f32x4 z = {0.f, 0.f, 0.f, 0.f};
#pragma unroll
  for (int mf = 0; mf < 4; ++mf)
#pragma unroll
    for (int nf = 0; nf < 4; ++nf) acc[mf][nf] = z;
  __builtin_amdgcn_s_setprio(1);
#pragma unroll
  for (int kc = 0; kc < 8; ++kc) {
    bf16x8 a[4], bb[4];
#pragma unroll
    for (int mf = 0; mf < 4; ++mf)
      a[mf] = *reinterpret_cast<const bf16x8*>(T + swz256(16 * mf + r16, 32 * kc + 8 * c4));
#pragma unroll
    for (int nf = 0; nf < 4; ++nf)
      bb[nf] = *reinterpret_cast<const bf16x8*>(pw + (nf * 8 + kc) * 512 + lane * 8);
#pragma unroll
    for (int mf = 0; mf < 4; ++mf)
#pragma unroll
      for (int nf = 0; nf < 4; ++nf) acc[mf][nf] = mfma16(a[mf], bb[nf], acc[mf][nf]);
  }
  __builtin_amdgcn_s_setprio(0);
}

// V epilogue (2 heads) — R7-verified
__device__ __forceinline__ void vFrag2(f32x4 acc[4][4], const float* __restrict__ bias,
                                       int lane, int w2, bf16x8 VfA[2][2], bf16x8 VfB[2][2]) {
  const int r16 = lane & 15, c4 = lane >> 4;
#pragma unroll
  for (int nf = 0; nf < 4; ++nf) {
    float bb = bias[64 * w2 + 16 * nf + r16];
#pragma unroll
    for (int mf = 0; mf < 4; ++mf)
#pragma unroll
      for (int r = 0; r < 4; ++r) acc[mf][nf][r] += bb;
  }
#pragma unroll
  for (int nf = 0; nf < 2; ++nf) {
    VfA[0][nf] = butterfly(acc[0][nf], acc[1][nf], c4, r16);
    VfA[1][nf] = butterfly(acc[2][nf], acc[3][nf], c4, r16);
    VfB[0][nf] = butterfly(acc[0][nf + 2], acc[1][nf + 2], c4, r16);
    VfB[1][nf] = butterfly(acc[2][nf + 2], acc[3][nf + 2], c4, r16);
  }
}

// PV half-rows (one head h): O[32 local rows][32 dims] -> BO cols [32h,32h+32)
__device__ __forceinline__ void pv_half(const bf16x8 Pf[2][2], const bf16x8 Vf[2][2],
                                        unsigned short* BO, int lane, int h) {
  const int r16 = lane & 15, c4 = lane >> 4;
  f32x4 z = {0.f, 0.f, 0.f, 0.f};
  f32x4 o[2][2];
#pragma unroll
  for (int qb2 = 0; qb2 < 2; ++qb2)
#pragma unroll
    for (int nf = 0; nf < 2; ++nf) o[qb2][nf] = z;
#pragma unroll
  for (int kc = 0; kc < 2; ++kc)
#pragma unroll
    for (int qb2 = 0; qb2 < 2; ++qb2)
#pragma unroll
      for (int nf = 0; nf < 2; ++nf)
        o[qb2][nf] = mfma16(Pf[qb2][kc], Vf[kc][nf], o[qb2][nf]);
#pragma unroll
  for (int qb2 = 0; qb2 < 2; ++qb2)
#pragma unroll
    for (int nf = 0; nf < 2; ++nf)
#pragma unroll
      for (int r = 0; r < 4; ++r)
        BO[swz256(16 * qb2 + 4 * c4 + r, 32 * h + 16 * nf + r16)] = f2bf(o[qb2][nf][r]);
}

// out-proj, half rows: BO[32][256] @ W^T (64 cols/wave), + bias, fp32 store
__device__ __forceinline__ void outProj_half(const unsigned short* __restrict__ BO,
                                             const unsigned short* __restrict__ pw,
                                             const float* __restrict__ bias,
                                             float* __restrict__ dst, int lane, int w2) {
  const int r16 = lane & 15, c4 = lane >> 4;
  f32x4 z = {0.f, 0.f, 0.f, 0.f};
  f32x4 acc[2][4];
#pragma unroll
  for (int mf = 0; mf < 2; ++mf)
#pragma unroll
    for (int nf = 0; nf < 4; ++nf) acc[mf][nf] = z;
  __builtin_amdgcn_s_setprio(1);
#pragma unroll
  for (int kc = 0; kc < 8; ++kc) {
    bf16x8 a[2], bb[4];
#pragma unroll
    for (int mf = 0; mf < 2; ++mf)
      a[mf] = *reinterpret_cast<const bf16x8*>(BO + swz256(16 * mf + r16, 32 * kc + 8 * c4));
#pragma unroll
    for (int nf = 0; nf < 4; ++nf)
      bb[nf] = *reinterpret_cast<const bf16x8*>(pw + (nf * 8 + kc) * 512 + lane * 8);
#pragma unroll
    for (int mf = 0; mf < 2; ++mf)
#pragma unroll
      for (int nf = 0; nf < 4; ++nf) acc[mf][nf] = mfma16(a[mf], bb[nf], acc[mf][nf]);
  }
  __builtin_amdgcn_s_setprio(0);
#pragma unroll
  for (int nf = 0; nf < 4; ++nf) {
    float bb = bias[64 * w2 + 16 * nf + r16];
#pragma unroll
    for (int mf = 0; mf < 2; ++mf)
#pragma unroll
      for (int r = 0; r < 4; ++r)
        dst[(16 * mf + 4 * c4 + r) * 256 + 64 * w2 + 16 * nf + r16] = acc[mf][nf][r] + bb;
  }
}

// ---------------- main fused kernel: (window, half) per block, 4 waves ------
// LDS 80KB: BO 16K (q-half -> O), A 32K (k -> sc), B 32K (v -> sh).
//  P0: stage q->BO, k->A                 P4: PV_s->BO; stage sh->B
//  P1: stage v->B; projT2 K(A);          P5: outProj_s(BO); projN64 Vh(B)
//      projT2q Q(BO); attn -> Pf         P6: PV_h->BO
//  P2: stage sc->A; projN64 V(B);        P7: outProj_h(BO)
//      PV_x->BO
//  P3: outProj_x(BO); projN64 Vs(A)
__global__ __launch_bounds__(256, 2) void win_attn(
    const float* __restrict__ gq, const float* __restrict__ gk, const float* __restrict__ gv,
    const float* __restrict__ gsc, const float* __restrict__ gsh,
    const unsigned short* __restrict__ pk,
    const float* __restrict__ b_q, const float* __restrict__ b_k, const float* __restrict__ b_v,
    const float* __restrict__ b_vs, const float* __restrict__ b_vh,
    const float* __restrict__ b_px, const float* __restrict__ b_ps, const float* __restrict__ b_ph,
    const float* __restrict__ bmt, float* __restrict__ out) {
  __shared__ __align__(16) unsigned short sm[40960];   // 80 KiB
  unsigned short* BO = sm;            // 16K: q-half, then O tile
  unsigned short* A  = sm + 8192;     // 32K: k, then sc
  unsigned short* B  = sm + 24576;    // 32K: v, then sh

  const int bid  = blockIdx.x;
  const int win  = (bid & 7) | ((bid >> 4) << 3);   // siblings 8 bids apart, same XCD
  const int hf   = (bid >> 3) & 1;                  // token half: rows hf*32..+32
  const int tid  = threadIdx.x;
  const int lane = tid & 63;
  const int w2   = tid >> 6;                        // wave 0..3: heads 2w2, 2w2+1
  const int wi   = win & 63;

  bf16x8 PfA[2][2], PfB[2][2];        // persistent: P for the wave's 2 heads
  bf16x8 VfA[2][2], VfB[2][2];

  const size_t outBase = (size_t)win * 16384 + (size_t)hf * 8192;

  // P0: stage q-half -> BO, k -> A
  stage_half(BO, gq, win, hf, tid);
  stage_tile(A, gk, win, tid);
  __syncthreads();                                    // bar0

  // P1: stage v -> B; K proj (full, A); Q proj (half, BO); attention
  {
    f32x4 r0[8], r1[8];
    load8(r0, gv, win, tid, 0);
    load8(r1, gv, win, tid, 1);
    bf16x8 KfA[4], KfB[4], QfA[2], QfB[2];
    projT2(A, pwBase7(pk, 1, w2), b_k, 1.0f, lane, w2, KfA, KfB);
    projT2q(BO, pwBase7(pk, 0, w2), b_q, 0.17677669529663687f, lane, w2, QfA, QfB);
    attn_half(QfA, KfA, bmt + ((size_t)(wi * 8 + 2 * w2) << 12), hf, lane, PfA);
    attn_half(QfB, KfB, bmt + ((size_t)(wi * 8 + 2 * w2 + 1) << 12), hf, lane, PfB);
    write8(B, r0, tid, 0);
    write8(B, r1, tid, 1);
  }
  __syncthreads();                                    // bar1

  // P2: stage sc -> A (k dead); V proj (full, B); PV_x -> BO (q dead)
  {
    f32x4 r0[8], r1[8];
    load8(r0, gsc, win, tid, 0);
    load8(r1, gsc, win, tid, 1);
    {
      f32x4 acc[4][4];
      projN64(B, pwBase7(pk, 2, w2), lane, acc);
      vFrag2(acc, b_v, lane, w2, VfA, VfB);
    }
    pv_half(PfA, VfA, BO, lane, 2 * w2);
    pv_half(PfB, VfB, BO, lane, 2 * w2 + 1);
    write8(A, r0, tid, 0);
    write8(A, r1, tid, 1);
  }
  __syncthreads();                                    // bar2

  // P3: outProj_x (BO); Vs proj (full, A=sc) -> Vf (held across bar)
  outProj_half(BO, pwBase7(pk, 5, w2), b_px, out + outBase, lane, w2);
  {
    f32x4 acc[4][4];
    projN64(A, pwBase7(pk, 3, w2), lane, acc);
    vFrag2(acc, b_vs, lane, w2, VfA, VfB);
  }
  __syncthreads();                                    // bar3

  // P4: PV_s -> BO; stage sh -> B (v dead)
  pv_half(PfA, VfA, BO, lane, 2 * w2);
  pv_half(PfB, VfB, BO, lane, 2 * w2 + 1);
  {
    f32x4 r0[8], r1[8];
    load8(r0, gsh, win, tid, 0);
    load8(r1, gsh, win, tid, 1);
    write8(B, r0, tid, 0);
    write8(B, r1, tid, 1);
  }
  __syncthreads();                                    // bar4

  // P5: outProj_s (BO); Vh proj (full, B=sh) -> Vf
  outProj_half(BO, pwBase7(pk, 6, w2), b_ps, out + 16777216 + outBase, lane, w2);
  {
    f32x4 acc[4][4];
    projN64(B, pwBase7(pk, 4, w2), lane, acc);
    vFrag2(acc, b_vh, lane, w2, VfA, VfB);
  }
  __syncthreads();                                    // bar5

  // P6: PV_h -> BO
  pv_half(PfA, VfA, BO, lane, 2 * w2);
  pv_half(PfB, VfB, BO, lane, 2 * w2 + 1);
  __syncthreads();                                    // bar6

  // P7: outProj_h (BO)
  outProj_half(BO, pwBase7(pk, 7, w2), b_ph, out + 33554432 + outBase, lane, w2);
}

// ---------------------------------------------------------------------------
extern "C" void kernel_launch(void* const* d_in, const int* in_sizes, int n_in,
                              void* d_out, int out_size, void* d_ws, size_t ws_size,
                              hipStream_t stream) {
  const float* Xq   = (const float*)d_in[0];
  const float* Xk   = (const float*)d_in[1];
  const float* Xv   = (const float*)d_in[2];
  const float* Xsc  = (const float*)d_in[3];
  const float* Xsh  = (const float*)d_in[4];
  const float* mask = (const float*)d_in[5];
  const float* Wq   = (const float*)d_in[6];  const float* bq  = (const float*)d_in[7];
  const float* Wk   = (const float*)d_in[8];  const float* bk  = (const float*)d_in[9];
  const float* Wv   = (const float*)d_in[10]; const float* bv  = (const float*)d_in[11];
  const float* Wvs  = (const float*)d_in[12]; const float* bvs = (const float*)d_in[13];
  const float* Wvh  = (const float*)d_in[14]; const float* bvh = (const float*)d_in[15];
  const float* Wpx  = (const float*)d_in[16]; const float* bpx = (const float*)d_in[17];
  const float* Wps  = (const float*)d_in[18]; const float* bps = (const float*)d_in[19];
  const float* Wph  = (const float*)d_in[20]; const float* bph = (const float*)d_in[21];
  const float* btab = (const float*)d_in[22];
  const int*   ridx = (const int*)d_in[23];

  unsigned short* pk = (unsigned short*)d_ws;                  // 8 mats x 128KB = 1 MB
  float* bmt = (float*)((char*)d_ws + (size_t)8 * 65536 * 2);  // 2M floats = 8 MB

  pack_weights<<<256, 256, 0, stream>>>(Wq, Wk, Wv, Wvs, Wvh, Wpx, Wps, Wph, pk);
  make_bmt<<<8192, 256, 0, stream>>>(mask, btab, ridx, bmt);
  win_attn<<<2048, 256, 0, stream>>>(Xq, Xk, Xv, Xsc, Xsh, pk,
                                     bq, bk, bv, bvs, bvh, bpx, bps, bph,
                                     bmt, (float*)d_out);
}